// Round 4
// baseline (31.079 us; speedup 1.0000x reference)
//
#include <hip/hip_runtime.h>

// RecModel fused kernel — round 4.
// 256-thread blocks (1 block = one 16-row tile, 1024 blocks, 4 blocks/CU),
// 3 barriers, shfl-combined history, nt-sliced waves (no B redundancy),
// full-coverage A1 writes (no zero phase), constant-trip unrolled gather loops.

using u16 = unsigned short;
typedef __attribute__((ext_vector_type(8))) short short8v;
typedef __attribute__((ext_vector_type(4))) short short4v;
typedef __attribute__((ext_vector_type(4))) float floatx4;

constexpr int W1_ELEMS = 13 * 8 * 64 * 8;  // 53248
constexpr int W2_ELEMS = 5 * 7 * 64 * 8;   // 17920

__device__ __forceinline__ u16 f2bf(float f) {
  unsigned u = __float_as_uint(f);
  unsigned r = (u + 0x7fffu + ((u >> 16) & 1u)) >> 16;  // RN-even
  return (u16)r;
}
__device__ __forceinline__ float bf2f(u16 h) {
  return __uint_as_float(((unsigned)h) << 16);
}

// ---- precompute: fc1/fc2 weights -> bf16 fragment arrays in ws ----
__global__ void build_frags(const float* __restrict__ w1, const float* __restrict__ w2,
                            u16* __restrict__ w1h, u16* __restrict__ w2h) {
  int tid = blockIdx.x * blockDim.x + threadIdx.x;
  if (tid < 13 * 8 * 64) {  // fc1 frags
    int l = tid & 63;
    int g = tid >> 6;
    int kt = g & 7, nt = g >> 3;
    int n = nt * 16 + (l & 15);
    int kb = kt * 32 + (l >> 4) * 8;
    short8v h8;
#pragma unroll
    for (int e = 0; e < 8; ++e) {
      int k = kb + e;
      float v = (n < 200 && k < 241) ? w1[n * 241 + k] : 0.f;
      h8[e] = (short)f2bf(v);
    }
    *(short8v*)&w1h[tid * 8] = h8;
  } else if (tid < 13 * 8 * 64 + 5 * 7 * 64) {  // fc2 frags
    int t2 = tid - 13 * 8 * 64;
    int l = t2 & 63;
    int g = t2 >> 6;
    int kt = g % 7, nt = g / 7;
    int n = nt * 16 + (l & 15);  // < 80
    int kb = kt * 32 + (l >> 4) * 8;
    short8v h8;
#pragma unroll
    for (int e = 0; e < 8; ++e) {
      int k = kb + e;
      float v = (k < 200) ? w2[n * 200 + k] : 0.f;
      h8[e] = (short)f2bf(v);
    }
    *(short8v*)&w2h[t2 * 8] = h8;
  }
}

// ---- main fused kernel: 256 threads = 4 waves, one 16-row tile ----
__global__ __launch_bounds__(256, 4) void fused_kernel(
    const int* __restrict__ sf, const float* __restrict__ dense,
    const int* __restrict__ hist, const float* __restrict__ W,
    const u16* __restrict__ w1h, const u16* __restrict__ w2h,
    const float* __restrict__ b1, const float* __restrict__ b2,
    const float* __restrict__ w3, const float* __restrict__ b3,
    float* __restrict__ out) {
  __shared__ u16 A1h[8 * 64 * 8], A1l[8 * 64 * 8];  // 8KB each
  __shared__ u16 A2h[7 * 64 * 8], A2l[7 * 64 * 8];  // 7KB each
  __shared__ float o2[16 * 84];                     // 5.25KB

  const int tid = threadIdx.x;
  const int l = tid & 63;
  const int wv = tid >> 6;
  const int row0 = blockIdx.x * 16;
  short8v z8 = {0, 0, 0, 0, 0, 0, 0, 0};

  // wave nt-slices for GEMM1: {0..3}, {4..6}, {7..9}, {10..12}
  const int ntbase = (wv == 0) ? 0 : 4 + 3 * (wv - 1);
  const int ntcnt = (wv == 0) ? 4 : 3;

  // early GEMM1 B prefetch (kt = 0,1) — independent of gather
  short8v bhr[2][4];
#pragma unroll
  for (int kk = 0; kk < 2; ++kk)
#pragma unroll
    for (int i = 0; i < 4; ++i)
      bhr[kk][i] = (i < ntcnt) ? *(const short8v*)&w1h[(((ntbase + i) * 8 + kk) * 64 + l) * 8]
                               : z8;

  // ---- embeddings: 896 quad-gathers over 256 threads ----
#pragma unroll
  for (int it = 0; it < 4; ++it) {
    int g = tid + it * 256;
    if (g < 896) {
      int q = g & 3, rt = g >> 2;
      int r = rt & 15, t = rt >> 4;
      int idx = sf[(row0 + r) * 14 + t] + 1;
      const float* p = W + ((size_t)t * 100001 + (size_t)idx) * 16 + q * 4;
      int k0 = t * 16 + q * 4;
      int kt = k0 >> 5, kg = (k0 >> 3) & 3, e0 = k0 & 7;
      short4v h4, l4;
#pragma unroll
      for (int d = 0; d < 4; ++d) {
        float v = p[d];
        u16 hi = f2bf(v);
        h4[d] = (short)hi;
        l4[d] = (short)f2bf(v - bf2f(hi));
      }
      int base = (kt * 64 + kg * 16 + r) * 8 + e0;
      *(short4v*)&A1h[base] = h4;
      *(short4v*)&A1l[base] = l4;
    }
  }

  // ---- history: 16 thr/row (q dim-quad x s stride-4 split), shfl combine ----
  {
    int r = tid >> 4, rem = tid & 15, q = rem & 3, s = rem >> 2;
    const int* hp = hist + (row0 + r) * 50;
    const float* Wq = W + q * 4;
    float a0 = 0.f, a1 = 0.f, a2 = 0.f, a3 = 0.f;
#pragma unroll
    for (int hh = 0; hh < 12; ++hh) {  // constant trip: h = s + 4*hh
      int idx = hp[s + hh * 4] + 1;    // in [1,100000]; row 0 never hit
      const float* p = Wq + (size_t)idx * 16;
      a0 += p[0];
      a1 += p[1];
      a2 += p[2];
      a3 += p[3];
    }
    if (s < 2) {  // tail: h = 48+s
      int idx = hp[48 + s] + 1;
      const float* p = Wq + (size_t)idx * 16;
      a0 += p[0];
      a1 += p[1];
      a2 += p[2];
      a3 += p[3];
    }
    // combine the 4 s-partials (s = tid bits 2..3) via shfl_xor
    a0 += __shfl_xor(a0, 4);
    a1 += __shfl_xor(a1, 4);
    a2 += __shfl_xor(a2, 4);
    a3 += __shfl_xor(a3, 4);
    a0 += __shfl_xor(a0, 8);
    a1 += __shfl_xor(a1, 8);
    a2 += __shfl_xor(a2, 8);
    a3 += __shfl_xor(a3, 8);
    if (s == 0) {
      float vals[4] = {a0, a1, a2, a3};
      short4v h4, l4;
#pragma unroll
      for (int d = 0; d < 4; ++d) {
        u16 hi = f2bf(vals[d]);
        h4[d] = (short)hi;
        l4[d] = (short)f2bf(vals[d] - bf2f(hi));
      }
      // k = 224 + q*4 + d -> kt=7, kg=q>>1, e0=(q*4)&7
      int base = (7 * 64 + (q >> 1) * 16 + r) * 8 + ((q * 4) & 7);
      *(short4v*)&A1h[base] = h4;
      *(short4v*)&A1l[base] = l4;
      if (q == 0) {
        // dense at k=240 (kt=7,kg=2,e=0) + zeros k=241..255
        float dv = dense[row0 + r];
        u16 dh = f2bf(dv), dl = f2bf(dv - bf2f(dh));
        short8v dh8 = z8, dl8 = z8;
        dh8[0] = (short)dh;
        dl8[0] = (short)dl;
        *(short8v*)&A1h[(7 * 64 + 32 + r) * 8] = dh8;
        *(short8v*)&A1l[(7 * 64 + 32 + r) * 8] = dl8;
        *(short8v*)&A1h[(7 * 64 + 48 + r) * 8] = z8;
        *(short8v*)&A1l[(7 * 64 + 48 + r) * 8] = z8;
      }
    }
  }
  __syncthreads();  // barrier 1: A1 complete

  // ---- GEMM1: each wave, its nt slice, all 8 kt; 2-kt-deep B prefetch ----
  floatx4 acc[4];
#pragma unroll
  for (int i = 0; i < 4; ++i) acc[i] = (floatx4){0.f, 0.f, 0.f, 0.f};

#pragma unroll
  for (int kt = 0; kt < 8; ++kt) {
    short8v ah = *(const short8v*)&A1h[(kt * 64 + l) * 8];
    short8v al = *(const short8v*)&A1l[(kt * 64 + l) * 8];
#pragma unroll
    for (int i = 0; i < 4; ++i) {
      if (i < ntcnt) {
        short8v cb = bhr[kt & 1][i];
        if (kt < 6) bhr[kt & 1][i] = *(const short8v*)&w1h[(((ntbase + i) * 8 + kt + 2) * 64 + l) * 8];
        acc[i] = __builtin_amdgcn_mfma_f32_16x16x32_bf16(ah, cb, acc[i], 0, 0, 0);
        acc[i] = __builtin_amdgcn_mfma_f32_16x16x32_bf16(al, cb, acc[i], 0, 0, 0);
      }
    }
  }

  // GEMM2 B prefetch (kt2 = 0,1) — issue before epilogue1 VALU work
  const int ntA = wv;  // all 4 waves valid; wave0 also handles nt2=4
  short8v bra[2], brb[2];
  bra[0] = *(const short8v*)&w2h[((ntA * 7 + 0) * 64 + l) * 8];
  bra[1] = *(const short8v*)&w2h[((ntA * 7 + 1) * 64 + l) * 8];
  if (wv == 0) {
    brb[0] = *(const short8v*)&w2h[((4 * 7 + 0) * 64 + l) * 8];
    brb[1] = *(const short8v*)&w2h[((4 * 7 + 1) * 64 + l) * 8];
  } else {
    brb[0] = z8;
    brb[1] = z8;
  }

  // ---- epilogue1: bias+relu -> A2 fragments (hi/lo), incl. zero pads ----
#pragma unroll
  for (int i = 0; i < 4; ++i) {
    if (i < ntcnt) {
      int n = (ntbase + i) * 16 + (l & 15);
      float bias = (n < 200) ? b1[n] : 0.f;
#pragma unroll
      for (int g = 0; g < 4; ++g) {
        float v = (n < 200) ? fmaxf(acc[i][g] + bias, 0.f) : 0.f;
        int m = (l >> 4) * 4 + g;
        u16 hi = f2bf(v), lo = f2bf(v - bf2f(hi));
        int kt2 = n >> 5, kg2 = (n >> 3) & 3, e = n & 7;
        int pos = (kt2 * 64 + kg2 * 16 + m) * 8 + e;
        A2h[pos] = hi;
        A2l[pos] = lo;
      }
    }
  }
  // zero k2 in [208,224): kt2=6, lanes 32..63
  if (wv == 1 && l < 32) {
    *(short8v*)&A2h[(6 * 64 + 32 + l) * 8] = z8;
    *(short8v*)&A2l[(6 * 64 + 32 + l) * 8] = z8;
  }
  __syncthreads();  // barrier 2: A2 complete

  // ---- GEMM2: wave wv -> nt2=wv; wave0 also nt2=4 ----
  floatx4 acca = (floatx4){0.f, 0.f, 0.f, 0.f};
  floatx4 accb = (floatx4){0.f, 0.f, 0.f, 0.f};
#pragma unroll
  for (int kt = 0; kt < 7; ++kt) {
    short8v ah = *(const short8v*)&A2h[(kt * 64 + l) * 8];
    short8v al = *(const short8v*)&A2l[(kt * 64 + l) * 8];
    short8v ca = bra[kt & 1];
    if (kt < 5) bra[kt & 1] = *(const short8v*)&w2h[((ntA * 7 + kt + 2) * 64 + l) * 8];
    acca = __builtin_amdgcn_mfma_f32_16x16x32_bf16(ah, ca, acca, 0, 0, 0);
    acca = __builtin_amdgcn_mfma_f32_16x16x32_bf16(al, ca, acca, 0, 0, 0);
    if (wv == 0) {
      short8v cb = brb[kt & 1];
      if (kt < 5) brb[kt & 1] = *(const short8v*)&w2h[((4 * 7 + kt + 2) * 64 + l) * 8];
      accb = __builtin_amdgcn_mfma_f32_16x16x32_bf16(ah, cb, accb, 0, 0, 0);
      accb = __builtin_amdgcn_mfma_f32_16x16x32_bf16(al, cb, accb, 0, 0, 0);
    }
  }

  // ---- epilogue2: bias+relu -> o2 [16][84] ----
  {
    int n = ntA * 16 + (l & 15);  // < 80
    float bias = b2[n];
#pragma unroll
    for (int g = 0; g < 4; ++g) {
      int r = (l >> 4) * 4 + g;
      o2[r * 84 + n] = fmaxf(acca[g] + bias, 0.f);
    }
    if (wv == 0) {
      int n2 = 64 + (l & 15);
      float bias2 = b2[n2];
#pragma unroll
      for (int g = 0; g < 4; ++g) {
        int r = (l >> 4) * 4 + g;
        o2[r * 84 + n2] = fmaxf(accb[g] + bias2, 0.f);
      }
    }
  }
  __syncthreads();  // barrier 3: o2 complete

  // ---- fc3 (fp32 VALU, float4 dots) ----
  if (tid < 32) {
    int r = tid >> 1, o = tid & 1;
    float a = b3[o];
    const float* orow = &o2[r * 84];
    const float* wrow = &w3[o * 80];
#pragma unroll
    for (int j = 0; j < 80; j += 4) {
      floatx4 xv = *(const floatx4*)&orow[j];
      floatx4 wv4 = *(const floatx4*)&wrow[j];
      a += xv[0] * wv4[0] + xv[1] * wv4[1] + xv[2] * wv4[2] + xv[3] * wv4[3];
    }
    out[(row0 + r) * 2 + o] = a;
  }
}

extern "C" void kernel_launch(void* const* d_in, const int* in_sizes, int n_in,
                              void* d_out, int out_size, void* d_ws, size_t ws_size,
                              hipStream_t stream) {
  const int* sf = (const int*)d_in[0];
  const float* dense = (const float*)d_in[1];
  const int* hist = (const int*)d_in[2];
  const float* W = (const float*)d_in[3];
  const float* w1 = (const float*)d_in[4];
  const float* b1 = (const float*)d_in[5];
  const float* w2 = (const float*)d_in[6];
  const float* b2 = (const float*)d_in[7];
  const float* w3 = (const float*)d_in[8];
  const float* b3 = (const float*)d_in[9];
  float* out = (float*)d_out;

  u16* w1h = (u16*)d_ws;
  u16* w2h = w1h + W1_ELEMS;

  build_frags<<<dim3(35), dim3(256), 0, stream>>>(w1, w2, w1h, w2h);
  fused_kernel<<<dim3(1024), dim3(256), 0, stream>>>(sf, dense, hist, W, w1h, w2h,
                                                     b1, b2, w3, b3, out);
}

// Round 5
// 30.281 us; speedup vs baseline: 1.0263x; 1.0263x over previous
//
#include <hip/hip_runtime.h>

// RecModel fused kernel — round 5.
// vs round 4: W0 (history table) converted to bf16 in precompute (3.2 MB ->
// fits per-XCD L2), history gathers 16B/lane from bf16; embedding lo-term
// dropped (A1-lo only for kt=7) -> GEMM1 9 MFMAs/nt instead of 16.

using u16 = unsigned short;
typedef __attribute__((ext_vector_type(8))) short short8v;
typedef __attribute__((ext_vector_type(4))) short short4v;
typedef __attribute__((ext_vector_type(4))) float floatx4;

constexpr int W1_ELEMS = 13 * 8 * 64 * 8;  // 53248
constexpr int W2_ELEMS = 5 * 7 * 64 * 8;   // 17920
constexpr int W0_ROWS = 100001;
constexpr int W0_ELEMS = W0_ROWS * 16;     // 1600016

__device__ __forceinline__ u16 f2bf(float f) {
  unsigned u = __float_as_uint(f);
  unsigned r = (u + 0x7fffu + ((u >> 16) & 1u)) >> 16;  // RN-even
  return (u16)r;
}
__device__ __forceinline__ float bf2f(u16 h) {
  return __uint_as_float(((unsigned)h) << 16);
}

// ---- precompute: weight frags + W0 -> bf16 ----
__global__ void precompute(const float* __restrict__ w1, const float* __restrict__ w2,
                           const float* __restrict__ W,
                           u16* __restrict__ w1h, u16* __restrict__ w2h,
                           u16* __restrict__ w0b) {
  int b = blockIdx.x;
  if (b < 35) {
    int tid = b * 256 + threadIdx.x;
    if (tid < 13 * 8 * 64) {  // fc1 frags
      int l = tid & 63;
      int g = tid >> 6;
      int kt = g & 7, nt = g >> 3;
      int n = nt * 16 + (l & 15);
      int kb = kt * 32 + (l >> 4) * 8;
      short8v h8;
#pragma unroll
      for (int e = 0; e < 8; ++e) {
        int k = kb + e;
        float v = (n < 200 && k < 241) ? w1[n * 241 + k] : 0.f;
        h8[e] = (short)f2bf(v);
      }
      *(short8v*)&w1h[tid * 8] = h8;
    } else if (tid < 13 * 8 * 64 + 5 * 7 * 64) {  // fc2 frags
      int t2 = tid - 13 * 8 * 64;
      int l = t2 & 63;
      int g = t2 >> 6;
      int kt = g % 7, nt = g / 7;
      int n = nt * 16 + (l & 15);
      int kb = kt * 32 + (l >> 4) * 8;
      short8v h8;
#pragma unroll
      for (int e = 0; e < 8; ++e) {
        int k = kb + e;
        float v = (k < 200) ? w2[n * 200 + k] : 0.f;
        h8[e] = (short)f2bf(v);
      }
      *(short8v*)&w2h[t2 * 8] = h8;
    }
  } else {
    // W0 -> bf16: 8 floats per thread
    int t = (b - 35) * 256 + threadIdx.x;
    int base = t * 8;
    if (base < W0_ELEMS) {
      floatx4 f0 = *(const floatx4*)(W + base);
      floatx4 f1 = *(const floatx4*)(W + base + 4);
      short8v o;
      o[0] = (short)f2bf(f0[0]);
      o[1] = (short)f2bf(f0[1]);
      o[2] = (short)f2bf(f0[2]);
      o[3] = (short)f2bf(f0[3]);
      o[4] = (short)f2bf(f1[0]);
      o[5] = (short)f2bf(f1[1]);
      o[6] = (short)f2bf(f1[2]);
      o[7] = (short)f2bf(f1[3]);
      *(short8v*)(w0b + base) = o;
    }
  }
}

// ---- main fused kernel: 256 threads = 4 waves, one 16-row tile ----
__global__ __launch_bounds__(256, 4) void fused_kernel(
    const int* __restrict__ sf, const float* __restrict__ dense,
    const int* __restrict__ hist, const float* __restrict__ W,
    const u16* __restrict__ w0b,
    const u16* __restrict__ w1h, const u16* __restrict__ w2h,
    const float* __restrict__ b1, const float* __restrict__ b2,
    const float* __restrict__ w3, const float* __restrict__ b3,
    float* __restrict__ out) {
  __shared__ u16 A1h[8 * 64 * 8];                   // 8KB
  __shared__ u16 A1l7[64 * 8];                      // 1KB (lo only for kt=7)
  __shared__ u16 A2h[7 * 64 * 8], A2l[7 * 64 * 8];  // 7KB each
  __shared__ float o2[16 * 84];                     // 5.25KB

  const int tid = threadIdx.x;
  const int l = tid & 63;
  const int wv = tid >> 6;
  const int row0 = blockIdx.x * 16;
  short8v z8 = {0, 0, 0, 0, 0, 0, 0, 0};

  // wave nt-slices for GEMM1: {0..3}, {4..6}, {7..9}, {10..12}
  const int ntbase = (wv == 0) ? 0 : 4 + 3 * (wv - 1);
  const int ntcnt = (wv == 0) ? 4 : 3;

  // early GEMM1 B prefetch (kt = 0,1) — independent of gather
  short8v bhr[2][4];
#pragma unroll
  for (int kk = 0; kk < 2; ++kk)
#pragma unroll
    for (int i = 0; i < 4; ++i)
      bhr[kk][i] = (i < ntcnt) ? *(const short8v*)&w1h[(((ntbase + i) * 8 + kk) * 64 + l) * 8]
                               : z8;

  // ---- embeddings: 896 quad-gathers (fp32, hi only) ----
#pragma unroll
  for (int it = 0; it < 4; ++it) {
    int g = tid + it * 256;
    if (g < 896) {
      int q = g & 3, rt = g >> 2;
      int r = rt & 15, t = rt >> 4;
      int idx = sf[(row0 + r) * 14 + t] + 1;
      const floatx4 v4 = *(const floatx4*)(W + ((size_t)t * 100001 + (size_t)idx) * 16 + q * 4);
      int k0 = t * 16 + q * 4;  // 0..220 -> kt 0..6
      int kt = k0 >> 5, kg = (k0 >> 3) & 3, e0 = k0 & 7;
      short4v h4;
#pragma unroll
      for (int d = 0; d < 4; ++d) h4[d] = (short)f2bf(v4[d]);
      *(short4v*)&A1h[(kt * 64 + kg * 16 + r) * 8 + e0] = h4;
    }
  }

  // ---- history: 16 thr/row = q(2 halves of 16 dims) x s(8-way split), bf16 W0 ----
  {
    int r = tid >> 4, rem = tid & 15, q = rem & 1, s = rem >> 1;
    const int* hp = hist + (row0 + r) * 50;
    const u16* Wq = w0b + q * 8;
    float a[8] = {0.f, 0.f, 0.f, 0.f, 0.f, 0.f, 0.f, 0.f};
#pragma unroll
    for (int hh = 0; hh < 6; ++hh) {  // h = s + 8*hh, constant trip
      int idx = hp[s + hh * 8] + 1;   // in [1,100000]
      short8v v = *(const short8v*)(Wq + (size_t)idx * 16);
#pragma unroll
      for (int d = 0; d < 8; ++d) a[d] += bf2f((u16)v[d]);
    }
    if (s < 2) {  // tail: h = 48+s
      int idx = hp[48 + s] + 1;
      short8v v = *(const short8v*)(Wq + (size_t)idx * 16);
#pragma unroll
      for (int d = 0; d < 8; ++d) a[d] += bf2f((u16)v[d]);
    }
    // combine 8 s-partials (s = tid bits 1..3) via shfl_xor
#pragma unroll
    for (int d = 0; d < 8; ++d) {
      a[d] += __shfl_xor(a[d], 2);
      a[d] += __shfl_xor(a[d], 4);
      a[d] += __shfl_xor(a[d], 8);
    }
    if (s == 0) {
      // dims k = 224 + q*8 + d -> kt=7, kg=q, e=d
      short8v h8, l8;
#pragma unroll
      for (int d = 0; d < 8; ++d) {
        u16 hi = f2bf(a[d]);
        h8[d] = (short)hi;
        l8[d] = (short)f2bf(a[d] - bf2f(hi));
      }
      *(short8v*)&A1h[(7 * 64 + q * 16 + r) * 8] = h8;
      *(short8v*)&A1l7[(q * 16 + r) * 8] = l8;
      if (q == 0) {
        // dense at k=240 (kg=2,e=0); zeros k=241..255
        float dv = dense[row0 + r];
        u16 dh = f2bf(dv), dl = f2bf(dv - bf2f(dh));
        short8v dh8 = z8, dl8 = z8;
        dh8[0] = (short)dh;
        dl8[0] = (short)dl;
        *(short8v*)&A1h[(7 * 64 + 32 + r) * 8] = dh8;
        *(short8v*)&A1l7[(32 + r) * 8] = dl8;
        *(short8v*)&A1h[(7 * 64 + 48 + r) * 8] = z8;
        *(short8v*)&A1l7[(48 + r) * 8] = z8;
      }
    }
  }
  __syncthreads();  // barrier 1: A1 complete

  // ---- GEMM1: hi for all 8 kt, lo only kt=7 ----
  floatx4 acc[4];
#pragma unroll
  for (int i = 0; i < 4; ++i) acc[i] = (floatx4){0.f, 0.f, 0.f, 0.f};

#pragma unroll
  for (int kt = 0; kt < 8; ++kt) {
    short8v ah = *(const short8v*)&A1h[(kt * 64 + l) * 8];
    short8v al7;
    if (kt == 7) al7 = *(const short8v*)&A1l7[l * 8];
#pragma unroll
    for (int i = 0; i < 4; ++i) {
      if (i < ntcnt) {
        short8v cb = bhr[kt & 1][i];
        if (kt < 6) bhr[kt & 1][i] = *(const short8v*)&w1h[(((ntbase + i) * 8 + kt + 2) * 64 + l) * 8];
        acc[i] = __builtin_amdgcn_mfma_f32_16x16x32_bf16(ah, cb, acc[i], 0, 0, 0);
        if (kt == 7) acc[i] = __builtin_amdgcn_mfma_f32_16x16x32_bf16(al7, cb, acc[i], 0, 0, 0);
      }
    }
  }

  // GEMM2 B prefetch (kt2 = 0,1)
  const int ntA = wv;  // wave0 also handles nt2=4
  short8v bra[2], brb[2];
  bra[0] = *(const short8v*)&w2h[((ntA * 7 + 0) * 64 + l) * 8];
  bra[1] = *(const short8v*)&w2h[((ntA * 7 + 1) * 64 + l) * 8];
  if (wv == 0) {
    brb[0] = *(const short8v*)&w2h[((4 * 7 + 0) * 64 + l) * 8];
    brb[1] = *(const short8v*)&w2h[((4 * 7 + 1) * 64 + l) * 8];
  } else {
    brb[0] = z8;
    brb[1] = z8;
  }

  // ---- epilogue1: bias+relu -> A2 fragments (hi/lo) ----
#pragma unroll
  for (int i = 0; i < 4; ++i) {
    if (i < ntcnt) {
      int n = (ntbase + i) * 16 + (l & 15);
      float bias = (n < 200) ? b1[n] : 0.f;
#pragma unroll
      for (int g = 0; g < 4; ++g) {
        float v = (n < 200) ? fmaxf(acc[i][g] + bias, 0.f) : 0.f;
        int m = (l >> 4) * 4 + g;
        u16 hi = f2bf(v), lo = f2bf(v - bf2f(hi));
        int kt2 = n >> 5, kg2 = (n >> 3) & 3, e = n & 7;
        int pos = (kt2 * 64 + kg2 * 16 + m) * 8 + e;
        A2h[pos] = hi;
        A2l[pos] = lo;
      }
    }
  }
  // zero k2 in [208,224): kt2=6, lanes 32..63
  if (wv == 1 && l < 32) {
    *(short8v*)&A2h[(6 * 64 + 32 + l) * 8] = z8;
    *(short8v*)&A2l[(6 * 64 + 32 + l) * 8] = z8;
  }
  __syncthreads();  // barrier 2: A2 complete

  // ---- GEMM2: wave wv -> nt2=wv; wave0 also nt2=4 ----
  floatx4 acca = (floatx4){0.f, 0.f, 0.f, 0.f};
  floatx4 accb = (floatx4){0.f, 0.f, 0.f, 0.f};
#pragma unroll
  for (int kt = 0; kt < 7; ++kt) {
    short8v ah = *(const short8v*)&A2h[(kt * 64 + l) * 8];
    short8v al = *(const short8v*)&A2l[(kt * 64 + l) * 8];
    short8v ca = bra[kt & 1];
    if (kt < 5) bra[kt & 1] = *(const short8v*)&w2h[((ntA * 7 + kt + 2) * 64 + l) * 8];
    acca = __builtin_amdgcn_mfma_f32_16x16x32_bf16(ah, ca, acca, 0, 0, 0);
    acca = __builtin_amdgcn_mfma_f32_16x16x32_bf16(al, ca, acca, 0, 0, 0);
    if (wv == 0) {
      short8v cb = brb[kt & 1];
      if (kt < 5) brb[kt & 1] = *(const short8v*)&w2h[((4 * 7 + kt + 2) * 64 + l) * 8];
      accb = __builtin_amdgcn_mfma_f32_16x16x32_bf16(ah, cb, accb, 0, 0, 0);
      accb = __builtin_amdgcn_mfma_f32_16x16x32_bf16(al, cb, accb, 0, 0, 0);
    }
  }

  // ---- epilogue2: bias+relu -> o2 [16][84] ----
  {
    int n = ntA * 16 + (l & 15);
    float bias = b2[n];
#pragma unroll
    for (int g = 0; g < 4; ++g) {
      int r = (l >> 4) * 4 + g;
      o2[r * 84 + n] = fmaxf(acca[g] + bias, 0.f);
    }
    if (wv == 0) {
      int n2 = 64 + (l & 15);
      float bias2 = b2[n2];
#pragma unroll
      for (int g = 0; g < 4; ++g) {
        int r = (l >> 4) * 4 + g;
        o2[r * 84 + n2] = fmaxf(accb[g] + bias2, 0.f);
      }
    }
  }
  __syncthreads();  // barrier 3: o2 complete

  // ---- fc3 (fp32 VALU, float4 dots) ----
  if (tid < 32) {
    int r = tid >> 1, o = tid & 1;
    float a = b3[o];
    const float* orow = &o2[r * 84];
    const float* wrow = &w3[o * 80];
#pragma unroll
    for (int j = 0; j < 80; j += 4) {
      floatx4 xv = *(const floatx4*)&orow[j];
      floatx4 wv4 = *(const floatx4*)&wrow[j];
      a += xv[0] * wv4[0] + xv[1] * wv4[1] + xv[2] * wv4[2] + xv[3] * wv4[3];
    }
    out[(row0 + r) * 2 + o] = a;
  }
}

extern "C" void kernel_launch(void* const* d_in, const int* in_sizes, int n_in,
                              void* d_out, int out_size, void* d_ws, size_t ws_size,
                              hipStream_t stream) {
  const int* sf = (const int*)d_in[0];
  const float* dense = (const float*)d_in[1];
  const int* hist = (const int*)d_in[2];
  const float* W = (const float*)d_in[3];
  const float* w1 = (const float*)d_in[4];
  const float* b1 = (const float*)d_in[5];
  const float* w2 = (const float*)d_in[6];
  const float* b2 = (const float*)d_in[7];
  const float* w3 = (const float*)d_in[8];
  const float* b3 = (const float*)d_in[9];
  float* out = (float*)d_out;

  u16* w1h = (u16*)d_ws;
  u16* w2h = w1h + W1_ELEMS;
  u16* w0b = w2h + W2_ELEMS;  // byte offset 142336 (16B aligned)

  int conv_blocks = (W0_ELEMS / 8 + 255) / 256;  // 782
  precompute<<<dim3(35 + conv_blocks), dim3(256), 0, stream>>>(w1, w2, W, w1h, w2h, w0b);
  fused_kernel<<<dim3(1024), dim3(256), 0, stream>>>(sf, dense, hist, W, w0b, w1h, w2h,
                                                     b1, b2, w3, b3, out);
}